// Round 13
// baseline (180.653 us; speedup 1.0000x reference)
//
#include <hip/hip_runtime.h>
#include <hip/hip_cooperative_groups.h>

namespace cg = cooperative_groups;

#define BGRAPH  16
#define NPG     8192     // 2^13 nodes per graph
#define DIM     256
#define KKEEP   4096     // 2^12 kept per graph
#define TOTALN  (BGRAPH * NPG)     // 131072
#define TOTKEEP (BGRAPH * KKEEP)   // 65536
#define NEDGE   2097152
#define NBUCK   8192     // 13-bit buckets (skey packs low-19 key bits + 13-bit idx)

#define NBLK    256
#define NTHR    1024     // 16 waves/block; grid = 4096 waves / 262144 threads

using u16 = unsigned short;
using u32 = unsigned int;

// descending-sortable transform of f32 bits: smaller kd <=> larger float
__device__ __forceinline__ u32 desc_key(float f) {
  u32 b = __float_as_uint(f);
  u32 s = b ^ ((b & 0x80000000u) ? 0xFFFFFFFFu : 0x80000000u);  // asc-sortable
  return ~s;                                                     // desc-sortable
}

// ---------------- phase A: score = tanh((x . w) / ||w||) --------------------
// wave-per-row, 32 rows/wave; w fragment + w2 reduction hoisted (bit-identical
// to per-row computation). NO atomics (R9 lesson).
__device__ __forceinline__ void phase_score(int gwave, int lane,
                                            const float* __restrict__ x,
                                            const float* __restrict__ w,
                                            float* __restrict__ score) {
  const float4 w4 = *reinterpret_cast<const float4*>(w + lane * 4);
  double w2 = (double)w4.x * w4.x + (double)w4.y * w4.y
            + (double)w4.z * w4.z + (double)w4.w * w4.w;
  #pragma unroll
  for (int off = 32; off > 0; off >>= 1) w2 += __shfl_xor(w2, off, 64);
  const double rn = sqrt(w2);
  #pragma unroll 4
  for (int i = 0; i < 32; ++i) {
    int row = gwave * 32 + i;
    const float4 x4 = *reinterpret_cast<const float4*>(x + (size_t)row * DIM + lane * 4);
    double dot = (double)x4.x * w4.x + (double)x4.y * w4.y
               + (double)x4.z * w4.z + (double)x4.w * w4.w;
    #pragma unroll
    for (int off = 32; off > 0; off >>= 1) dot += __shfl_xor(dot, off, 64);
    if (lane == 0) score[row] = tanhf((float)(dot / rn));
  }
}

// ---------------- phase B: bucket-sort, 1 block/graph (blocks 0..15) --------
// hist+scan+scatter all in LDS (proven best structure; no cross-XCD sharing).
__device__ __forceinline__ void phase_sort(int blk, int tid,
                                           const float* __restrict__ score,
                                           u32* __restrict__ skey,
                                           u32* __restrict__ bends,
                                           u32* __restrict__ gceil) {
  __shared__ u32 hist[NBUCK];                // 32 KB
  __shared__ u32 wsum[16];
  if (blk >= BGRAPH) return;
  const int g    = blk;
  const int wid  = tid >> 6;
  const int lane = tid & 63;
  const float* gs = score + ((size_t)g << 13);
  u32* skg = skey  + ((size_t)g << 13);
  u32* beg = bends + ((size_t)g << 13);

  #pragma unroll
  for (int i = 0; i < NBUCK / NTHR; ++i) hist[tid + i * NTHR] = 0;
  __syncthreads();

  u32 kd_[NPG / NTHR];
  #pragma unroll
  for (int i = 0; i < NPG / NTHR; ++i) {
    kd_[i] = desc_key(gs[tid + i * NTHR]);
    atomicAdd(&hist[kd_[i] >> 19], 1u);
  }
  __syncthreads();

  u32 h[8], s = 0;
  #pragma unroll
  for (int j = 0; j < 8; ++j) { h[j] = hist[8 * tid + j]; s += h[j]; }
  u32 inc = s;
  #pragma unroll
  for (int off = 1; off < 64; off <<= 1) {
    u32 t = __shfl_up(inc, off, 64);
    if (lane >= off) inc += t;
  }
  if (lane == 63) wsum[wid] = inc;
  __syncthreads();
  if (tid < 16) {
    u32 v = wsum[tid], vi = v;
    #pragma unroll
    for (int off = 1; off < 16; off <<= 1) {
      u32 t = __shfl_up(vi, off, 64);
      if (tid >= off) vi += t;
    }
    wsum[tid] = vi - v;                      // exclusive wave offset
  }
  __syncthreads();
  u32 run = inc - s + wsum[wid];             // exclusive start of this thread's 8
  #pragma unroll
  for (int j = 0; j < 8; ++j) {
    u32 hv  = h[j];
    u32 end = run + hv;
    hist[8 * tid + j] = run;                 // cursor = bucket start
    beg[8 * tid + j]  = end;                 // bucket end -> global
    if (run < KKEEP && end >= KKEEP) gceil[g] = end;   // exactly one bucket
    run = end;
  }
  __syncthreads();

  #pragma unroll
  for (int i = 0; i < NPG / NTHR; ++i) {
    int idx = tid + i * NTHR;
    u32 pos = atomicAdd(&hist[kd_[i] >> 19], 1u);
    skg[pos] = (kd_[i] << 13) | (u32)idx;    // one-u32 stable comparator
  }
}

// ---------------- phase C: rank count + map16 + inverse permutation ---------
__device__ __forceinline__ void phase_count(int t,
                                            const float* __restrict__ score,
                                            const u32* __restrict__ skey,
                                            const u32* __restrict__ bends,
                                            const u32* __restrict__ gceil,
                                            u16* __restrict__ map16,
                                            u16* __restrict__ inv) {
  if (t >= TOTALN) return;
  const int g = t >> 13;
  const int p = t & (NPG - 1);
  const size_t gb = ((size_t)g << 13);
  const u32* skg = skey + gb;
  u32 key = skg[p];
  int idx = (int)(key & 0x1FFFu);
  if ((u32)p >= gceil[g]) { map16[gb + idx] = (u16)0xFFFFu; return; }
  u32 b = desc_key(score[gb + idx]) >> 19;
  const u32* beg = bends + gb;
  u32 start = b ? beg[b - 1] : 0;
  u32 end   = beg[b];
  u32 cnt = 0, q = start;
  for (; q + 4 <= end; q += 4) {             // branchless
    cnt += (skg[q]     < key) + (skg[q + 1] < key)
         + (skg[q + 2] < key) + (skg[q + 3] < key);
  }
  for (; q < end; ++q) cnt += (skg[q] < key);
  u32 rank = start + cnt;
  if (rank < KKEEP) {
    map16[gb + idx] = (u16)rank;
    inv[((u32)g << 12) | rank] = (u16)idx;   // inverse perm (claimed exactly once)
  } else {
    map16[gb + idx] = (u16)0xFFFFu;
  }
}

// ---------------- phase D: gather via inverse perm (no idle waves) ----------
__device__ __forceinline__ void phase_gather(int gwave, int lane,
                                             const float* __restrict__ x,
                                             const float* __restrict__ score,
                                             const u16* __restrict__ inv,
                                             float* __restrict__ x_out) {
  #pragma unroll 4
  for (int i = 0; i < 16; ++i) {
    int r = gwave * 16 + i;                  // output row 0..65535
    int idx  = (int)inv[r];                  // broadcast load
    int node = ((r >> 12) << 13) | idx;
    float val = score[node];
    const float4 v = *reinterpret_cast<const float4*>(x + (size_t)node * DIM + lane * 4);
    float4 o;
    o.x = v.x * val; o.y = v.y * val; o.z = v.z * val; o.w = v.w * val;
    *reinterpret_cast<float4*>(x_out + (size_t)r * DIM + lane * 4) = o;
  }
}

// ---------------- phase E: edges (8/thread) + batch -------------------------
__device__ __forceinline__ void edges4(const int4 a, const int4 b,
                                       const u16* __restrict__ map16,
                                       float4& es, float4& ed) {
  u16 ra0 = map16[a.x], ra1 = map16[a.y], ra2 = map16[a.z], ra3 = map16[a.w];
  u16 rb0 = map16[b.x], rb1 = map16[b.y], rb2 = map16[b.z], rb3 = map16[b.w];
  bool k0 = (ra0 != 0xFFFFu) && (rb0 != 0xFFFFu);
  bool k1 = (ra1 != 0xFFFFu) && (rb1 != 0xFFFFu);
  bool k2 = (ra2 != 0xFFFFu) && (rb2 != 0xFFFFu);
  bool k3 = (ra3 != 0xFFFFu) && (rb3 != 0xFFFFu);
  es.x = k0 ? (float)(((a.x >> 13) << 12) | ra0) : -1.0f;
  es.y = k1 ? (float)(((a.y >> 13) << 12) | ra1) : -1.0f;
  es.z = k2 ? (float)(((a.z >> 13) << 12) | ra2) : -1.0f;
  es.w = k3 ? (float)(((a.w >> 13) << 12) | ra3) : -1.0f;
  ed.x = k0 ? (float)(((b.x >> 13) << 12) | rb0) : -1.0f;
  ed.y = k1 ? (float)(((b.y >> 13) << 12) | rb1) : -1.0f;
  ed.z = k2 ? (float)(((b.z >> 13) << 12) | rb2) : -1.0f;
  ed.w = k3 ? (float)(((b.w >> 13) << 12) | rb3) : -1.0f;
}

__device__ __forceinline__ void phase_edges(int t,
                                            const int* __restrict__ ei,
                                            const u16* __restrict__ map16,
                                            float* __restrict__ e_out,
                                            float* __restrict__ b_out) {
  size_t e8 = (size_t)t * 8;
  const int4 a0 = *reinterpret_cast<const int4*>(ei + e8);
  const int4 a1 = *reinterpret_cast<const int4*>(ei + e8 + 4);
  const int4 d0 = *reinterpret_cast<const int4*>(ei + NEDGE + e8);
  const int4 d1 = *reinterpret_cast<const int4*>(ei + NEDGE + e8 + 4);
  float4 s0, dd0, s1, dd1;
  edges4(a0, d0, map16, s0, dd0);
  edges4(a1, d1, map16, s1, dd1);
  *reinterpret_cast<float4*>(e_out + e8)             = s0;
  *reinterpret_cast<float4*>(e_out + e8 + 4)         = s1;
  *reinterpret_cast<float4*>(e_out + NEDGE + e8)     = dd0;
  *reinterpret_cast<float4*>(e_out + NEDGE + e8 + 4) = dd1;
  if (t < TOTKEEP / 4) {                     // batch: nid / K = graph id
    float gf = (float)(t >> 10);
    float4 bo; bo.x = gf; bo.y = gf; bo.z = gf; bo.w = gf;
    *reinterpret_cast<float4*>(b_out + 4 * (size_t)t) = bo;
  }
}

// ---------------- cooperative mega-kernel (1 dispatch, 3 grid syncs) --------
__global__ __launch_bounds__(NTHR) void k_mega(const float* __restrict__ x,
                                               const float* __restrict__ w,
                                               const int* __restrict__ ei,
                                               float* __restrict__ score,
                                               u32* __restrict__ skey,
                                               u32* __restrict__ bends,
                                               u32* __restrict__ gceil,
                                               u16* __restrict__ map16,
                                               u16* __restrict__ inv,
                                               float* __restrict__ x_out,
                                               float* __restrict__ e_out,
                                               float* __restrict__ b_out) {
  cg::grid_group grid = cg::this_grid();
  const int blk = blockIdx.x, tid = threadIdx.x;
  const int lane  = tid & 63;
  const int gwave = blk * (NTHR / 64) + (tid >> 6);
  const int t     = blk * NTHR + tid;

  phase_score(gwave, lane, x, w, score);
  grid.sync();
  phase_sort(blk, tid, score, skey, bends, gceil);
  grid.sync();
  phase_count(t, score, skey, bends, gceil, map16, inv);
  grid.sync();
  phase_gather(gwave, lane, x, score, inv, x_out);   // D and E both depend
  phase_edges(t, ei, map16, e_out, b_out);           // only on C: no sync
}

// ---------------- fallback path: same phases as 4 plain dispatches ----------
__global__ __launch_bounds__(NTHR) void k_pA(const float* x, const float* w, float* score) {
  phase_score(blockIdx.x * (NTHR / 64) + (threadIdx.x >> 6), threadIdx.x & 63, x, w, score);
}
__global__ __launch_bounds__(NTHR) void k_pB(const float* score, u32* skey, u32* bends, u32* gceil) {
  phase_sort(blockIdx.x, threadIdx.x, score, skey, bends, gceil);
}
__global__ __launch_bounds__(NTHR) void k_pC(const float* score, const u32* skey, const u32* bends,
                                             const u32* gceil, u16* map16, u16* inv) {
  phase_count(blockIdx.x * NTHR + threadIdx.x, score, skey, bends, gceil, map16, inv);
}
__global__ __launch_bounds__(NTHR) void k_pDE(const float* x, const float* score, const u16* inv,
                                              const int* ei, const u16* map16,
                                              float* x_out, float* e_out, float* b_out) {
  phase_gather(blockIdx.x * (NTHR / 64) + (threadIdx.x >> 6), threadIdx.x & 63, x, score, inv, x_out);
  phase_edges(blockIdx.x * NTHR + threadIdx.x, ei, map16, e_out, b_out);
}

extern "C" void kernel_launch(void* const* d_in, const int* in_sizes, int n_in,
                              void* d_out, int out_size, void* d_ws, size_t ws_size,
                              hipStream_t stream) {
  const float* x  = nullptr;
  const int*   ei = nullptr;
  const float* w  = nullptr;
  for (int i = 0; i < n_in; ++i) {
    if      (in_sizes[i] == TOTALN * DIM) x  = (const float*)d_in[i];
    else if (in_sizes[i] == 2 * NEDGE)    ei = (const int*)d_in[i];
    else if (in_sizes[i] == DIM)          w  = (const float*)d_in[i];
  }
  (void)out_size; (void)ws_size;

  // d_out: FLOAT32, layout [x_out 16777216 | e_out 4194304 | b_out 65536]
  float* out   = (float*)d_out;
  float* x_out = out;
  float* e_out = out + (size_t)TOTKEEP * DIM;
  float* b_out = e_out + 2 * (size_t)NEDGE;

  // staging in d_ws (every consumed word is written earlier in this call)
  char* ws = (char*)d_ws;
  float* score = (float*)(ws);                         // 512 KB
  u32*   skey  = (u32*)(ws + (512  << 10));            // 512 KB [16][8192]
  u32*   bends = (u32*)(ws + (1024 << 10));            // 512 KB [16][8192]
  u16*   map16 = (u16*)(ws + (1536 << 10));            // 256 KB
  u16*   inv   = (u16*)(ws + (1792 << 10));            // 128 KB [16][4096]
  u32*   gceil = (u32*)(ws + (1920 << 10));            // 64 B

  void* args[] = {(void*)&x, (void*)&w, (void*)&ei, (void*)&score, (void*)&skey,
                  (void*)&bends, (void*)&gceil, (void*)&map16, (void*)&inv,
                  (void*)&x_out, (void*)&e_out, (void*)&b_out};
  hipError_t err = hipLaunchCooperativeKernel((const void*)k_mega, dim3(NBLK), dim3(NTHR),
                                              args, 0, stream);
  if (err != hipSuccess) {                   // fallback: same phases, 4 dispatches
    hipLaunchKernelGGL(k_pA,  dim3(NBLK), dim3(NTHR), 0, stream, x, w, score);
    hipLaunchKernelGGL(k_pB,  dim3(NBLK), dim3(NTHR), 0, stream, score, skey, bends, gceil);
    hipLaunchKernelGGL(k_pC,  dim3(NBLK), dim3(NTHR), 0, stream, score, skey, bends, gceil, map16, inv);
    hipLaunchKernelGGL(k_pDE, dim3(NBLK), dim3(NTHR), 0, stream, x, score, inv, ei, map16, x_out, e_out, b_out);
  }
}

// Round 14
// 92.227 us; speedup vs baseline: 1.9588x; 1.9588x over previous
//
#include <hip/hip_runtime.h>

#define BGRAPH  16
#define NPG     8192     // 2^13 nodes per graph
#define DIM     256
#define KKEEP   4096     // 2^12 kept per graph
#define TOTALN  (BGRAPH * NPG)     // 131072
#define TOTKEEP (BGRAPH * KKEEP)   // 65536
#define NEDGE   2097152
#define NBUCK   8192     // 13-bit buckets (skey packs low-19 key bits + 13-bit idx)

using u16 = unsigned short;
using u32 = unsigned int;

// descending-sortable transform of f32 bits: smaller kd <=> larger float
__device__ __forceinline__ u32 desc_key(float f) {
  u32 b = __float_as_uint(f);
  u32 s = b ^ ((b & 0x80000000u) ? 0xFFFFFFFFu : 0x80000000u);  // asc-sortable
  return ~s;                                                     // desc-sortable
}

// ---------------- kernel 1: score + map16 pre-init --------------------------
// one wave per row (proven form; NO atomics). First 65536 threads also
// pre-init map16 to 0xFFFF (u32 pairs) — consumed 2 kernels later.
__global__ __launch_bounds__(256) void k_score(const float* __restrict__ x,
                                               const float* __restrict__ w,
                                               float* __restrict__ score,
                                               u32* __restrict__ map32) {
  int gid  = blockIdx.x * 256 + threadIdx.x;
  if (gid < TOTALN / 2) map32[gid] = 0xFFFFFFFFu;
  int row  = gid >> 6;
  int lane = gid & 63;
  const float4 x4 = *reinterpret_cast<const float4*>(x + (size_t)row * DIM + lane * 4);
  const float4 w4 = *reinterpret_cast<const float4*>(w + lane * 4);
  double dot = (double)x4.x * w4.x + (double)x4.y * w4.y
             + (double)x4.z * w4.z + (double)x4.w * w4.w;
  double w2  = (double)w4.x * w4.x + (double)w4.y * w4.y
             + (double)w4.z * w4.z + (double)w4.w * w4.w;
  #pragma unroll
  for (int off = 32; off > 0; off >>= 1) {
    dot += __shfl_xor(dot, off, 64);
    w2  += __shfl_xor(w2,  off, 64);
  }
  if (lane == 0) score[row] = tanhf((float)(dot / sqrt(w2)));
}

// ---------------- kernel 2: monolithic bucket-sort (1 block/graph) ----------
// hist + scan + scatter in LDS (best-measured structure). NEW: boundary
// bucket bb computed in-scan; scatter skips buckets > bb (drop side).
__global__ __launch_bounds__(1024) void k_sort(const float* __restrict__ score,
                                               u32* __restrict__ skey,
                                               u32* __restrict__ bends,
                                               u32* __restrict__ gceil) {
  __shared__ u32 hist[NBUCK];                // 32 KB
  __shared__ u32 wsum[16];
  __shared__ u32 sbb;                        // boundary bucket id
  const int g    = blockIdx.x;
  const int tid  = threadIdx.x;
  const int wid  = tid >> 6;
  const int lane = tid & 63;
  const float* gs = score + ((size_t)g << 13);
  u32* skg = skey  + ((size_t)g << 13);
  u32* beg = bends + ((size_t)g << 13);

  #pragma unroll
  for (int i = 0; i < NBUCK / 1024; ++i) hist[tid + i * 1024] = 0;
  __syncthreads();

  u32 kd_[NPG / 1024];                       // keys cached in registers
  #pragma unroll
  for (int i = 0; i < NPG / 1024; ++i) {
    kd_[i] = desc_key(gs[tid + i * 1024]);
    atomicAdd(&hist[kd_[i] >> 19], 1u);
  }
  __syncthreads();

  u32 h[8], s = 0;
  #pragma unroll
  for (int j = 0; j < 8; ++j) { h[j] = hist[8 * tid + j]; s += h[j]; }
  u32 inc = s;
  #pragma unroll
  for (int off = 1; off < 64; off <<= 1) {
    u32 t = __shfl_up(inc, off, 64);
    if (lane >= off) inc += t;
  }
  if (lane == 63) wsum[wid] = inc;
  __syncthreads();
  if (tid < 16) {
    u32 v = wsum[tid], vi = v;
    #pragma unroll
    for (int off = 1; off < 16; off <<= 1) {
      u32 t = __shfl_up(vi, off, 64);
      if (tid >= off) vi += t;
    }
    wsum[tid] = vi - v;                      // exclusive wave offset
  }
  __syncthreads();
  u32 run = inc - s + wsum[wid];             // exclusive start of this thread's 8
  #pragma unroll
  for (int j = 0; j < 8; ++j) {
    u32 hv  = h[j];
    u32 end = run + hv;
    hist[8 * tid + j] = run;                 // cursor = bucket start
    beg[8 * tid + j]  = end;                 // bucket end -> global
    if (run < KKEEP && end >= KKEEP) {       // exactly one straddling bucket
      gceil[g] = end;
      sbb = (u32)(8 * tid + j);
    }
    run = end;
  }
  __syncthreads();

  // scatter KEPT-side buckets only (b <= bb); drop side never materialized
  const u32 bb = sbb;
  #pragma unroll
  for (int i = 0; i < NPG / 1024; ++i) {
    u32 kd = kd_[i];
    u32 b  = kd >> 19;
    if (b <= bb) {
      u32 pos = atomicAdd(&hist[b], 1u);
      skg[pos] = (kd << 13) | (u32)(tid + i * 1024);   // stable one-u32 comparator
    }
  }
}

// ---------------- kernel 3: rank count, kept region only --------------------
// map16 pre-inited to 0xFFFF; only kept writes happen here. Emits inverse
// permutation inv[g*K + rank] = idx for the dense gather.
__global__ __launch_bounds__(512) void k_count(const float* __restrict__ score,
                                               const u32* __restrict__ skey,
                                               const u32* __restrict__ bends,
                                               const u32* __restrict__ gceil,
                                               u16* __restrict__ map16,
                                               u16* __restrict__ inv) {
  const int g = blockIdx.x >> 4;
  const int p = (blockIdx.x & 15) * 512 + (int)threadIdx.x;
  if ((u32)p >= gceil[g]) return;            // drop side: never scattered
  const size_t gb = ((size_t)g << 13);
  const u32* skg = skey + gb;
  u32 key = skg[p];
  int idx = (int)(key & 0x1FFFu);
  u32 b = desc_key(score[gb + idx]) >> 19;   // bucket from L2-hot re-read
  const u32* beg = bends + gb;
  u32 start = b ? beg[b - 1] : 0;
  u32 end   = beg[b];
  u32 cnt = 0, q = start;
  for (; q + 4 <= end; q += 4) {             // branchless, wave-broadcast reads
    cnt += (skg[q]     < key) + (skg[q + 1] < key)
         + (skg[q + 2] < key) + (skg[q + 3] < key);
  }
  for (; q < end; ++q) cnt += (skg[q] < key);
  u32 rank = start + cnt;
  if (rank < KKEEP) {
    map16[gb + idx] = (u16)rank;
    inv[((u32)g << 12) | rank] = (u16)idx;   // claimed exactly once
  }
}

// ---------------- kernel 4: dense gather + edges + batch (role-split) -------
#define GB 16384   // gather blocks: 4 waves x 16384 = 65536 output rows
#define EB 1024    // edge blocks: 256 thr x 8 edges

__global__ __launch_bounds__(256) void k_ge(const float* __restrict__ x,
                                            const float* __restrict__ score,
                                            const u16* __restrict__ inv,
                                            const int* __restrict__ ei,
                                            const u16* __restrict__ map16,
                                            float* __restrict__ x_out,
                                            float* __restrict__ e_out,
                                            float* __restrict__ b_out) {
  const int blk = blockIdx.x;
  const int tid = threadIdx.x;
  if (blk < GB) {
    // ---- gather: wave per OUTPUT row (no idle lanes, coalesced both sides)
    int r    = blk * 4 + (tid >> 6);         // output row 0..65535
    int lane = tid & 63;
    int idx  = (int)inv[r];                  // broadcast load
    int node = ((r >> 12) << 13) | idx;
    float val = score[node];                 // broadcast load
    const float4 v = *reinterpret_cast<const float4*>(x + (size_t)node * DIM + lane * 4);
    float4 o;
    o.x = v.x * val; o.y = v.y * val; o.z = v.z * val; o.w = v.w * val;
    *reinterpret_cast<float4*>(x_out + (size_t)r * DIM + lane * 4) = o;
    return;
  }
  // ---- edges: 8 per thread, vectorized; first 16384 threads also write batch
  int t = (blk - GB) * 256 + tid;            // 0..262143
  size_t e8 = (size_t)t * 8;
  const int4 a0 = *reinterpret_cast<const int4*>(ei + e8);
  const int4 a1 = *reinterpret_cast<const int4*>(ei + e8 + 4);
  const int4 d0 = *reinterpret_cast<const int4*>(ei + NEDGE + e8);
  const int4 d1 = *reinterpret_cast<const int4*>(ei + NEDGE + e8 + 4);
  float4 s0, s1, dd0, dd1;
  {
    u16 ra0 = map16[a0.x], ra1 = map16[a0.y], ra2 = map16[a0.z], ra3 = map16[a0.w];
    u16 rb0 = map16[d0.x], rb1 = map16[d0.y], rb2 = map16[d0.z], rb3 = map16[d0.w];
    bool k0 = (ra0 != 0xFFFFu) && (rb0 != 0xFFFFu);
    bool k1 = (ra1 != 0xFFFFu) && (rb1 != 0xFFFFu);
    bool k2 = (ra2 != 0xFFFFu) && (rb2 != 0xFFFFu);
    bool k3 = (ra3 != 0xFFFFu) && (rb3 != 0xFFFFu);
    s0.x  = k0 ? (float)(((a0.x >> 13) << 12) | ra0) : -1.0f;
    s0.y  = k1 ? (float)(((a0.y >> 13) << 12) | ra1) : -1.0f;
    s0.z  = k2 ? (float)(((a0.z >> 13) << 12) | ra2) : -1.0f;
    s0.w  = k3 ? (float)(((a0.w >> 13) << 12) | ra3) : -1.0f;
    dd0.x = k0 ? (float)(((d0.x >> 13) << 12) | rb0) : -1.0f;
    dd0.y = k1 ? (float)(((d0.y >> 13) << 12) | rb1) : -1.0f;
    dd0.z = k2 ? (float)(((d0.z >> 13) << 12) | rb2) : -1.0f;
    dd0.w = k3 ? (float)(((d0.w >> 13) << 12) | rb3) : -1.0f;
  }
  {
    u16 ra0 = map16[a1.x], ra1 = map16[a1.y], ra2 = map16[a1.z], ra3 = map16[a1.w];
    u16 rb0 = map16[d1.x], rb1 = map16[d1.y], rb2 = map16[d1.z], rb3 = map16[d1.w];
    bool k0 = (ra0 != 0xFFFFu) && (rb0 != 0xFFFFu);
    bool k1 = (ra1 != 0xFFFFu) && (rb1 != 0xFFFFu);
    bool k2 = (ra2 != 0xFFFFu) && (rb2 != 0xFFFFu);
    bool k3 = (ra3 != 0xFFFFu) && (rb3 != 0xFFFFu);
    s1.x  = k0 ? (float)(((a1.x >> 13) << 12) | ra0) : -1.0f;
    s1.y  = k1 ? (float)(((a1.y >> 13) << 12) | ra1) : -1.0f;
    s1.z  = k2 ? (float)(((a1.z >> 13) << 12) | ra2) : -1.0f;
    s1.w  = k3 ? (float)(((a1.w >> 13) << 12) | ra3) : -1.0f;
    dd1.x = k0 ? (float)(((d1.x >> 13) << 12) | rb0) : -1.0f;
    dd1.y = k1 ? (float)(((d1.y >> 13) << 12) | rb1) : -1.0f;
    dd1.z = k2 ? (float)(((d1.z >> 13) << 12) | rb2) : -1.0f;
    dd1.w = k3 ? (float)(((d1.w >> 13) << 12) | rb3) : -1.0f;
  }
  *reinterpret_cast<float4*>(e_out + e8)             = s0;
  *reinterpret_cast<float4*>(e_out + e8 + 4)         = s1;
  *reinterpret_cast<float4*>(e_out + NEDGE + e8)     = dd0;
  *reinterpret_cast<float4*>(e_out + NEDGE + e8 + 4) = dd1;
  if (t < TOTKEEP / 4) {                     // batch: nid / K = graph id
    float gf = (float)(t >> 10);
    float4 bo; bo.x = gf; bo.y = gf; bo.z = gf; bo.w = gf;
    *reinterpret_cast<float4*>(b_out + 4 * (size_t)t) = bo;
  }
}

extern "C" void kernel_launch(void* const* d_in, const int* in_sizes, int n_in,
                              void* d_out, int out_size, void* d_ws, size_t ws_size,
                              hipStream_t stream) {
  const float* x  = nullptr;
  const int*   ei = nullptr;
  const float* w  = nullptr;
  for (int i = 0; i < n_in; ++i) {
    if      (in_sizes[i] == TOTALN * DIM) x  = (const float*)d_in[i];
    else if (in_sizes[i] == 2 * NEDGE)    ei = (const int*)d_in[i];
    else if (in_sizes[i] == DIM)          w  = (const float*)d_in[i];
  }
  (void)out_size; (void)ws_size;

  // d_out: FLOAT32, layout [x_out 16777216 | e_out 4194304 | b_out 65536]
  float* out   = (float*)d_out;
  float* x_out = out;
  float* e_out = out + (size_t)TOTKEEP * DIM;
  float* b_out = e_out + 2 * (size_t)NEDGE;

  // staging in d_ws (every consumed word is written earlier in this call)
  char* ws = (char*)d_ws;
  float* score = (float*)(ws);                         // 512 KB
  u32*   skey  = (u32*)(ws + (512  << 10));            // 512 KB [16][8192]
  u32*   bends = (u32*)(ws + (1024 << 10));            // 512 KB [16][8192]
  u16*   map16 = (u16*)(ws + (1536 << 10));            // 256 KB
  u16*   inv   = (u16*)(ws + (1792 << 10));            // 128 KB [16][4096]
  u32*   gceil = (u32*)(ws + (1920 << 10));            // 64 B

  hipLaunchKernelGGL(k_score, dim3(TOTALN / 4),  dim3(256),  0, stream,
                     x, w, score, (u32*)map16);
  hipLaunchKernelGGL(k_sort,  dim3(BGRAPH),      dim3(1024), 0, stream,
                     score, skey, bends, gceil);
  hipLaunchKernelGGL(k_count, dim3(BGRAPH * 16), dim3(512),  0, stream,
                     score, skey, bends, gceil, map16, inv);
  hipLaunchKernelGGL(k_ge,    dim3(GB + EB),     dim3(256),  0, stream,
                     x, score, inv, ei, map16, x_out, e_out, b_out);
}

// Round 15
// 77.083 us; speedup vs baseline: 2.3436x; 1.1965x over previous
//
#include <hip/hip_runtime.h>

#define BGRAPH  16
#define NPG     8192     // 2^13 nodes per graph
#define DIM     256
#define KKEEP   4096     // 2^12 kept per graph
#define TOTALN  (BGRAPH * NPG)     // 131072
#define TOTKEEP (BGRAPH * KKEEP)   // 65536
#define NEDGE   2097152
#define NBUCK   8192     // 13-bit buckets (skey packs low-19 key bits + 13-bit idx)

using u16 = unsigned short;
using u32 = unsigned int;

// descending-sortable transform of f32 bits: smaller kd <=> larger float
__device__ __forceinline__ u32 desc_key(float f) {
  u32 b = __float_as_uint(f);
  u32 s = b ^ ((b & 0x80000000u) ? 0xFFFFFFFFu : 0x80000000u);  // asc-sortable
  return ~s;                                                     // desc-sortable
}

// ---------------- kernel 1: score (f32, 2 rows/wave ILP) + map16 pre-init ---
// Reference computes the dot in f32; matching precision class costs nothing
// in accuracy (absmax headroom ~20x) and removes the f64 shuffle-chain that
// paced this kernel. Two independent butterflies interleave to hide latency.
__global__ __launch_bounds__(256) void k_score(const float* __restrict__ x,
                                               const float* __restrict__ w,
                                               float* __restrict__ score,
                                               u32* __restrict__ map32) {
  int gid  = blockIdx.x * 256 + threadIdx.x;
  if (gid < TOTALN / 2) map32[gid] = 0xFFFFFFFFu;
  int wv   = gid >> 6;                       // wave id: handles rows 2wv, 2wv+1
  int lane = gid & 63;
  size_t r0 = (size_t)(wv * 2);
  const float4 w4 = *reinterpret_cast<const float4*>(w + lane * 4);
  const float4 a  = *reinterpret_cast<const float4*>(x + r0 * DIM + lane * 4);
  const float4 b  = *reinterpret_cast<const float4*>(x + (r0 + 1) * DIM + lane * 4);
  float w2 = w4.x * w4.x + w4.y * w4.y + w4.z * w4.z + w4.w * w4.w;
  float d0 = a.x * w4.x + a.y * w4.y + a.z * w4.z + a.w * w4.w;
  float d1 = b.x * w4.x + b.y * w4.y + b.z * w4.z + b.w * w4.w;
  #pragma unroll
  for (int off = 32; off > 0; off >>= 1) {   // three interleaved butterflies
    d0 += __shfl_xor(d0, off, 64);
    d1 += __shfl_xor(d1, off, 64);
    w2 += __shfl_xor(w2, off, 64);
  }
  if (lane == 0) {
    float rn = sqrtf(w2);
    score[r0]     = tanhf(d0 / rn);
    score[r0 + 1] = tanhf(d1 / rn);
  }
}

// ---------------- kernel 2: monolithic bucket-sort (1 block/graph) ----------
// hist + scan + scatter in LDS (best-measured structure). Boundary bucket bb
// computed in-scan; scatter skips buckets > bb (drop side never materialized).
__global__ __launch_bounds__(1024) void k_sort(const float* __restrict__ score,
                                               u32* __restrict__ skey,
                                               u32* __restrict__ bends,
                                               u32* __restrict__ gceil) {
  __shared__ u32 hist[NBUCK];                // 32 KB
  __shared__ u32 wsum[16];
  __shared__ u32 sbb;                        // boundary bucket id
  const int g    = blockIdx.x;
  const int tid  = threadIdx.x;
  const int wid  = tid >> 6;
  const int lane = tid & 63;
  const float* gs = score + ((size_t)g << 13);
  u32* skg = skey  + ((size_t)g << 13);
  u32* beg = bends + ((size_t)g << 13);

  #pragma unroll
  for (int i = 0; i < NBUCK / 1024; ++i) hist[tid + i * 1024] = 0;
  __syncthreads();

  u32 kd_[NPG / 1024];                       // keys cached in registers
  #pragma unroll
  for (int i = 0; i < NPG / 1024; ++i) {
    kd_[i] = desc_key(gs[tid + i * 1024]);
    atomicAdd(&hist[kd_[i] >> 19], 1u);
  }
  __syncthreads();

  u32 h[8], s = 0;
  #pragma unroll
  for (int j = 0; j < 8; ++j) { h[j] = hist[8 * tid + j]; s += h[j]; }
  u32 inc = s;
  #pragma unroll
  for (int off = 1; off < 64; off <<= 1) {
    u32 t = __shfl_up(inc, off, 64);
    if (lane >= off) inc += t;
  }
  if (lane == 63) wsum[wid] = inc;
  __syncthreads();
  if (tid < 16) {
    u32 v = wsum[tid], vi = v;
    #pragma unroll
    for (int off = 1; off < 16; off <<= 1) {
      u32 t = __shfl_up(vi, off, 64);
      if (tid >= off) vi += t;
    }
    wsum[tid] = vi - v;                      // exclusive wave offset
  }
  __syncthreads();
  u32 run = inc - s + wsum[wid];             // exclusive start of this thread's 8
  #pragma unroll
  for (int j = 0; j < 8; ++j) {
    u32 hv  = h[j];
    u32 end = run + hv;
    hist[8 * tid + j] = run;                 // cursor = bucket start
    beg[8 * tid + j]  = end;                 // bucket end -> global
    if (run < KKEEP && end >= KKEEP) {       // exactly one straddling bucket
      gceil[g] = end;
      sbb = (u32)(8 * tid + j);
    }
    run = end;
  }
  __syncthreads();

  // scatter KEPT-side buckets only (b <= bb)
  const u32 bb = sbb;
  #pragma unroll
  for (int i = 0; i < NPG / 1024; ++i) {
    u32 kd = kd_[i];
    u32 b  = kd >> 19;
    if (b <= bb) {
      u32 pos = atomicAdd(&hist[b], 1u);
      skg[pos] = (kd << 13) | (u32)(tid + i * 1024);   // stable one-u32 comparator
    }
  }
}

// ---------------- kernel 3: rank count, kept region only (uint4 loads) ------
__global__ __launch_bounds__(512) void k_count(const float* __restrict__ score,
                                               const u32* __restrict__ skey,
                                               const u32* __restrict__ bends,
                                               const u32* __restrict__ gceil,
                                               u16* __restrict__ map16,
                                               u16* __restrict__ inv) {
  const int g = blockIdx.x >> 4;
  const int p = (blockIdx.x & 15) * 512 + (int)threadIdx.x;
  if ((u32)p >= gceil[g]) return;            // drop side: never scattered
  const size_t gb = ((size_t)g << 13);
  const u32* skg = skey + gb;
  u32 key = skg[p];
  int idx = (int)(key & 0x1FFFu);
  u32 b = desc_key(score[gb + idx]) >> 19;   // bucket from L2-hot re-read
  const u32* beg = bends + gb;
  u32 start = b ? beg[b - 1] : 0;
  u32 end   = beg[b];
  u32 cnt = 0, q = start;
  u32 qa = (start + 3u) & ~3u;               // first 16B-aligned position
  for (; q < qa && q < end; ++q) cnt += (skg[q] < key);          // head
  for (; q + 4 <= end; q += 4) {             // 16B vector loads, branchless
    uint4 v4 = *reinterpret_cast<const uint4*>(skg + q);
    cnt += (v4.x < key) + (v4.y < key) + (v4.z < key) + (v4.w < key);
  }
  for (; q < end; ++q) cnt += (skg[q] < key);                    // tail
  u32 rank = start + cnt;
  if (rank < KKEEP) {
    map16[gb + idx] = (u16)rank;
    inv[((u32)g << 12) | rank] = (u16)idx;   // claimed exactly once
  }
}

// ---------------- kernel 4: dense gather + edges + batch (role-split) -------
#define GB 16384   // gather blocks: 4 waves x 16384 = 65536 output rows
#define EB 1024    // edge blocks: 256 thr x 8 edges

__global__ __launch_bounds__(256) void k_ge(const float* __restrict__ x,
                                            const float* __restrict__ score,
                                            const u16* __restrict__ inv,
                                            const int* __restrict__ ei,
                                            const u16* __restrict__ map16,
                                            float* __restrict__ x_out,
                                            float* __restrict__ e_out,
                                            float* __restrict__ b_out) {
  const int blk = blockIdx.x;
  const int tid = threadIdx.x;
  if (blk < GB) {
    // ---- gather: wave per OUTPUT row (no idle lanes, coalesced both sides)
    int r    = blk * 4 + (tid >> 6);         // output row 0..65535
    int lane = tid & 63;
    int idx  = (int)inv[r];                  // broadcast load
    int node = ((r >> 12) << 13) | idx;
    float val = score[node];                 // broadcast load
    const float4 v = *reinterpret_cast<const float4*>(x + (size_t)node * DIM + lane * 4);
    float4 o;
    o.x = v.x * val; o.y = v.y * val; o.z = v.z * val; o.w = v.w * val;
    *reinterpret_cast<float4*>(x_out + (size_t)r * DIM + lane * 4) = o;
    return;
  }
  // ---- edges: 8 per thread, vectorized; first 16384 threads also write batch
  int t = (blk - GB) * 256 + tid;            // 0..262143
  size_t e8 = (size_t)t * 8;
  const int4 a0 = *reinterpret_cast<const int4*>(ei + e8);
  const int4 a1 = *reinterpret_cast<const int4*>(ei + e8 + 4);
  const int4 d0 = *reinterpret_cast<const int4*>(ei + NEDGE + e8);
  const int4 d1 = *reinterpret_cast<const int4*>(ei + NEDGE + e8 + 4);
  float4 s0, s1, dd0, dd1;
  {
    u16 ra0 = map16[a0.x], ra1 = map16[a0.y], ra2 = map16[a0.z], ra3 = map16[a0.w];
    u16 rb0 = map16[d0.x], rb1 = map16[d0.y], rb2 = map16[d0.z], rb3 = map16[d0.w];
    bool k0 = (ra0 != 0xFFFFu) && (rb0 != 0xFFFFu);
    bool k1 = (ra1 != 0xFFFFu) && (rb1 != 0xFFFFu);
    bool k2 = (ra2 != 0xFFFFu) && (rb2 != 0xFFFFu);
    bool k3 = (ra3 != 0xFFFFu) && (rb3 != 0xFFFFu);
    s0.x  = k0 ? (float)(((a0.x >> 13) << 12) | ra0) : -1.0f;
    s0.y  = k1 ? (float)(((a0.y >> 13) << 12) | ra1) : -1.0f;
    s0.z  = k2 ? (float)(((a0.z >> 13) << 12) | ra2) : -1.0f;
    s0.w  = k3 ? (float)(((a0.w >> 13) << 12) | ra3) : -1.0f;
    dd0.x = k0 ? (float)(((d0.x >> 13) << 12) | rb0) : -1.0f;
    dd0.y = k1 ? (float)(((d0.y >> 13) << 12) | rb1) : -1.0f;
    dd0.z = k2 ? (float)(((d0.z >> 13) << 12) | rb2) : -1.0f;
    dd0.w = k3 ? (float)(((d0.w >> 13) << 12) | rb3) : -1.0f;
  }
  {
    u16 ra0 = map16[a1.x], ra1 = map16[a1.y], ra2 = map16[a1.z], ra3 = map16[a1.w];
    u16 rb0 = map16[d1.x], rb1 = map16[d1.y], rb2 = map16[d1.z], rb3 = map16[d1.w];
    bool k0 = (ra0 != 0xFFFFu) && (rb0 != 0xFFFFu);
    bool k1 = (ra1 != 0xFFFFu) && (rb1 != 0xFFFFu);
    bool k2 = (ra2 != 0xFFFFu) && (rb2 != 0xFFFFu);
    bool k3 = (ra3 != 0xFFFFu) && (rb3 != 0xFFFFu);
    s1.x  = k0 ? (float)(((a1.x >> 13) << 12) | ra0) : -1.0f;
    s1.y  = k1 ? (float)(((a1.y >> 13) << 12) | ra1) : -1.0f;
    s1.z  = k2 ? (float)(((a1.z >> 13) << 12) | ra2) : -1.0f;
    s1.w  = k3 ? (float)(((a1.w >> 13) << 12) | ra3) : -1.0f;
    dd1.x = k0 ? (float)(((d1.x >> 13) << 12) | rb0) : -1.0f;
    dd1.y = k1 ? (float)(((d1.y >> 13) << 12) | rb1) : -1.0f;
    dd1.z = k2 ? (float)(((d1.z >> 13) << 12) | rb2) : -1.0f;
    dd1.w = k3 ? (float)(((d1.w >> 13) << 12) | rb3) : -1.0f;
  }
  *reinterpret_cast<float4*>(e_out + e8)             = s0;
  *reinterpret_cast<float4*>(e_out + e8 + 4)         = s1;
  *reinterpret_cast<float4*>(e_out + NEDGE + e8)     = dd0;
  *reinterpret_cast<float4*>(e_out + NEDGE + e8 + 4) = dd1;
  if (t < TOTKEEP / 4) {                     // batch: nid / K = graph id
    float gf = (float)(t >> 10);
    float4 bo; bo.x = gf; bo.y = gf; bo.z = gf; bo.w = gf;
    *reinterpret_cast<float4*>(b_out + 4 * (size_t)t) = bo;
  }
}

extern "C" void kernel_launch(void* const* d_in, const int* in_sizes, int n_in,
                              void* d_out, int out_size, void* d_ws, size_t ws_size,
                              hipStream_t stream) {
  const float* x  = nullptr;
  const int*   ei = nullptr;
  const float* w  = nullptr;
  for (int i = 0; i < n_in; ++i) {
    if      (in_sizes[i] == TOTALN * DIM) x  = (const float*)d_in[i];
    else if (in_sizes[i] == 2 * NEDGE)    ei = (const int*)d_in[i];
    else if (in_sizes[i] == DIM)          w  = (const float*)d_in[i];
  }
  (void)out_size; (void)ws_size;

  // d_out: FLOAT32, layout [x_out 16777216 | e_out 4194304 | b_out 65536]
  float* out   = (float*)d_out;
  float* x_out = out;
  float* e_out = out + (size_t)TOTKEEP * DIM;
  float* b_out = e_out + 2 * (size_t)NEDGE;

  // staging in d_ws (every consumed word is written earlier in this call)
  char* ws = (char*)d_ws;
  float* score = (float*)(ws);                         // 512 KB
  u32*   skey  = (u32*)(ws + (512  << 10));            // 512 KB [16][8192]
  u32*   bends = (u32*)(ws + (1024 << 10));            // 512 KB [16][8192]
  u16*   map16 = (u16*)(ws + (1536 << 10));            // 256 KB
  u16*   inv   = (u16*)(ws + (1792 << 10));            // 128 KB [16][4096]
  u32*   gceil = (u32*)(ws + (1920 << 10));            // 64 B

  hipLaunchKernelGGL(k_score, dim3(TOTALN / 8),  dim3(256),  0, stream,
                     x, w, score, (u32*)map16);        // 2 rows/wave
  hipLaunchKernelGGL(k_sort,  dim3(BGRAPH),      dim3(1024), 0, stream,
                     score, skey, bends, gceil);
  hipLaunchKernelGGL(k_count, dim3(BGRAPH * 16), dim3(512),  0, stream,
                     score, skey, bends, gceil, map16, inv);
  hipLaunchKernelGGL(k_ge,    dim3(GB + EB),     dim3(256),  0, stream,
                     x, score, inv, ei, map16, x_out, e_out, b_out);
}